// Round 1
// baseline (186.609 us; speedup 1.0000x reference)
//
#include <hip/hip_runtime.h>
#include <math.h>

// ---- problem constants ----
#define NN      4096   // nodes
#define INF_    512    // in features
#define OUTF    256    // out features
#define NHEAD   4
#define HDIM    64
#define KSPLIT  8

typedef __attribute__((ext_vector_type(8))) short  short8x;
typedef __attribute__((ext_vector_type(4))) float  float4x;
typedef __attribute__((ext_vector_type(2))) float  float2x;

__device__ __forceinline__ unsigned short f2bf(float x) {
    union { float f; unsigned int u; } c; c.f = x;
    unsigned int r = (c.u + 0x7FFFu + ((c.u >> 16) & 1u)) >> 16;
    return (unsigned short)r;
}
// unpack a bf16 pair (one dword) into float2 {lo, hi}
__device__ __forceinline__ float2x bf2up(unsigned int u) {
    union { unsigned int x; float f; } lo, hi;
    lo.x = u << 16; hi.x = u & 0xFFFF0000u;
    float2x r; r[0] = lo.f; r[1] = hi.f; return r;
}
__device__ __forceinline__ float2x max2(float2x a, float2x b) {
    float2x r; r[0] = fmaxf(a[0], b[0]); r[1] = fmaxf(a[1], b[1]); return r;
}

// ============================================================
// K0: cast feat and W to bf16
// ============================================================
__global__ __launch_bounds__(256) void k_cast(const float* __restrict__ feat,
                                              const float* __restrict__ W,
                                              unsigned short* __restrict__ featb,
                                              unsigned short* __restrict__ Wb) {
    const int b = blockIdx.x;
    const float* src;
    unsigned short* dst;
    int idx;
    if (b < 2048) { src = feat; dst = featb; idx = b * 1024 + threadIdx.x * 4; }
    else          { src = W;    dst = Wb;    idx = (b - 2048) * 1024 + threadIdx.x * 4; }
    float4x v = *(const float4x*)(src + idx);
    ushort4 u;
    u.x = f2bf(v[0]); u.y = f2bf(v[1]); u.z = f2bf(v[2]); u.w = f2bf(v[3]);
    *(ushort4*)(dst + idx) = u;
}

// ============================================================
// K1: h = feat @ W^T (bf16 MFMA, 64 blocks, full OUTF per block)
// epilogue: hT bf16 write + es/ed per-head dots from registers
// -> es + exp tables Bt=exp(ed), Dt=exp(0.2 ed)
// ============================================================
__global__ __launch_bounds__(256) void k_hedge(const unsigned short* __restrict__ featb,
                                               const unsigned short* __restrict__ Wb,
                                               const float* __restrict__ a,
                                               unsigned short* __restrict__ hT,
                                               float* __restrict__ es,
                                               unsigned short* __restrict__ Bt,
                                               unsigned short* __restrict__ Dt) {
    __shared__ __align__(16) unsigned short lds_f[64 * 40];
    __shared__ __align__(16) unsigned short lds_w[256 * 40];
    const int tid  = threadIdx.x;
    const int w    = tid >> 6;
    const int lane = tid & 63;
    const int lidx = lane & 15;
    const int quad = lane >> 4;
    const int i0   = blockIdx.x * 64;
    const int sr = tid >> 2;
    const int skq = (tid & 3) * 8;

    float4x acc[4][4];
    #pragma unroll
    for (int p = 0; p < 4; ++p)
        #pragma unroll
        for (int q = 0; q < 4; ++q)
            acc[p][q] = (float4x){0.f, 0.f, 0.f, 0.f};

    for (int kt = 0; kt < INF_; kt += 32) {
        __syncthreads();
        *(ushort4*)&lds_f[sr * 40 + skq]     = *(const ushort4*)&featb[(size_t)(i0 + sr) * INF_ + kt + skq];
        *(ushort4*)&lds_f[sr * 40 + skq + 4] = *(const ushort4*)&featb[(size_t)(i0 + sr) * INF_ + kt + skq + 4];
        #pragma unroll
        for (int itr = 0; itr < 4; ++itr) {
            int n = itr * 64 + sr;
            *(ushort4*)&lds_w[n * 40 + skq]     = *(const ushort4*)&Wb[(size_t)n * INF_ + kt + skq];
            *(ushort4*)&lds_w[n * 40 + skq + 4] = *(const ushort4*)&Wb[(size_t)n * INF_ + kt + skq + 4];
        }
        __syncthreads();
        short8x af[4], bw[4];
        #pragma unroll
        for (int t = 0; t < 4; ++t) {
            af[t] = *(const short8x*)&lds_f[(t * 16 + lidx) * 40 + quad * 8];
            bw[t] = *(const short8x*)&lds_w[(w * 64 + t * 16 + lidx) * 40 + quad * 8];
        }
        #pragma unroll
        for (int it = 0; it < 4; ++it)
            #pragma unroll
            for (int nt = 0; nt < 4; ++nt)
                acc[it][nt] = __builtin_amdgcn_mfma_f32_16x16x32_bf16(
                    af[it], bw[nt], acc[it][nt], 0, 0, 0);
    }
    // ---- hT write (D layout: col=lane&15 block w*64+nt*16, row=quad*4+r) ----
    #pragma unroll
    for (int it = 0; it < 4; ++it)
        #pragma unroll
        for (int nt = 0; nt < 4; ++nt) {
            int col = w * 64 + nt * 16 + lidx;
            int m0r = i0 + it * 16 + quad * 4;
            ushort4 u;
            u.x = f2bf(acc[it][nt][0]); u.y = f2bf(acc[it][nt][1]);
            u.z = f2bf(acc[it][nt][2]); u.w = f2bf(acc[it][nt][3]);
            *(ushort4*)&hT[(size_t)col * NN + m0r] = u;
        }
    // ---- es/ed epilogue: head = w; col_d = nt*16 + lidx ----
    float asrc[4], adst[4];
    #pragma unroll
    for (int nt = 0; nt < 4; ++nt) {
        asrc[nt] = a[w * 2 * HDIM + nt * 16 + lidx];
        adst[nt] = a[w * 2 * HDIM + HDIM + nt * 16 + lidx];
    }
    #pragma unroll
    for (int it = 0; it < 4; ++it)
        #pragma unroll
        for (int r = 0; r < 4; ++r) {
            float s = 0.f, d = 0.f;
            #pragma unroll
            for (int nt = 0; nt < 4; ++nt) {
                s += acc[it][nt][r] * asrc[nt];
                d += acc[it][nt][r] * adst[nt];
            }
            #pragma unroll
            for (int off = 1; off < 16; off <<= 1) {
                s += __shfl_xor(s, off);
                d += __shfl_xor(d, off);
            }
            if (lidx == 0) {
                int row = i0 + it * 16 + quad * 4 + r;
                es[row * NHEAD + w] = s;
                Bt[row * NHEAD + w] = f2bf(__expf(d));
                Dt[row * NHEAD + w] = f2bf(__expf(0.2f * d));
            }
        }
}

// ============================================================
// K2: fused den + attn-row write. 1 row/block, 4096 blocks (16/CU).
// Max-trick: exp(leaky(es+ed)) = max(A*b, C*d) with A=exp(es),
// C=exp(0.2 es), b=exp(ed), d=exp(0.2 ed). No sign-test, single
// accumulator per head, mask folded as x{0,1} fma. float2-packed
// math for v_pk_mul/v_pk_fma_f32. adj cached in regs across passes.
// ============================================================
__global__ __launch_bounds__(256) void k_attn(const float* __restrict__ adj,
                                              const float* __restrict__ es,
                                              const unsigned short* __restrict__ Bt,
                                              const unsigned short* __restrict__ Dt,
                                              unsigned short* __restrict__ attn) {
    __shared__ float red[4][4];
    __shared__ float cfs[4];
    const int tid = threadIdx.x;
    const int wv  = tid >> 6;
    const int lane = tid & 63;
    const int i = blockIdx.x;

    const float4x esv = ((const float4x*)es)[i];
    float2x A01, A23, C01, C23;
    A01[0] = __expf(esv[0]); A01[1] = __expf(esv[1]);
    A23[0] = __expf(esv[2]); A23[1] = __expf(esv[3]);
    C01[0] = __expf(0.2f * esv[0]); C01[1] = __expf(0.2f * esv[1]);
    C23[0] = __expf(0.2f * esv[2]); C23[1] = __expf(0.2f * esv[3]);

    const float4x* arow4 = (const float4x*)(adj + (size_t)i * NN);
    const uint4* B4 = (const uint4*)Bt;
    const uint4* D4 = (const uint4*)Dt;

    // ---- pass 1: masked den sums (adj row -> regs, tables inline) ----
    float4x av[4];
    float2x den01 = (float2x){0.f, 0.f};
    float2x den23 = (float2x){0.f, 0.f};
    #pragma unroll
    for (int t = 0; t < 4; ++t) {
        int jv = t * 256 + tid;
        av[t] = arow4[jv];
        uint4 bu0 = B4[jv * 2], bu1 = B4[jv * 2 + 1];
        uint4 du0 = D4[jv * 2], du1 = D4[jv * 2 + 1];
        unsigned int bwv[8] = {bu0.x, bu0.y, bu0.z, bu0.w, bu1.x, bu1.y, bu1.z, bu1.w};
        unsigned int dwv[8] = {du0.x, du0.y, du0.z, du0.w, du1.x, du1.y, du1.z, du1.w};
        #pragma unroll
        for (int u = 0; u < 4; ++u) {
            float2x b01 = bf2up(bwv[u * 2]);
            float2x b23 = bf2up(bwv[u * 2 + 1]);
            float2x d01 = bf2up(dwv[u * 2]);
            float2x d23 = bf2up(dwv[u * 2 + 1]);
            float mf = (av[t][u] > 0.1f) ? 1.f : 0.f;
            float2x mf2; mf2[0] = mf; mf2[1] = mf;
            float2x t01 = max2(A01 * b01, C01 * d01);
            float2x t23 = max2(A23 * b23, C23 * d23);
            den01 += mf2 * t01;
            den23 += mf2 * t23;
        }
    }
    float dh[4] = {den01[0], den01[1], den23[0], den23[1]};
    #pragma unroll
    for (int off = 1; off < 64; off <<= 1) {
        #pragma unroll
        for (int h = 0; h < 4; ++h)
            dh[h] += __shfl_xor(dh[h], off);
    }
    if (lane == 0) {
        #pragma unroll
        for (int h = 0; h < 4; ++h) red[wv][h] = dh[h];
    }
    __syncthreads();
    if (tid < 4)
        cfs[tid] = red[0][tid] + red[1][tid] + red[2][tid] + red[3][tid];
    __syncthreads();
    float2x cA01, cA23, cC01, cC23;
    {
        float sc[4];
        #pragma unroll
        for (int h = 0; h < 4; ++h) {
            float den = cfs[h];
            sc[h] = den > 0.f ? 0.25f / den : 0.f;
        }
        cA01 = A01; cA23 = A23; cC01 = C01; cC23 = C23;
        cA01[0] *= sc[0]; cA01[1] *= sc[1]; cA23[0] *= sc[2]; cA23[1] *= sc[3];
        cC01[0] *= sc[0]; cC01[1] *= sc[1]; cC23[0] *= sc[2]; cC23[1] *= sc[3];
    }

    // ---- pass 2: re-read tables (L2-hot), adj from regs, store ----
    unsigned short* orow = attn + (size_t)i * NN;
    #pragma unroll
    for (int t = 0; t < 4; ++t) {
        int jv = t * 256 + tid;
        uint4 bu0 = B4[jv * 2], bu1 = B4[jv * 2 + 1];
        uint4 du0 = D4[jv * 2], du1 = D4[jv * 2 + 1];
        unsigned int bwv[8] = {bu0.x, bu0.y, bu0.z, bu0.w, bu1.x, bu1.y, bu1.z, bu1.w};
        unsigned int dwv[8] = {du0.x, du0.y, du0.z, du0.w, du1.x, du1.y, du1.z, du1.w};
        ushort4 o;
        unsigned short* op = (unsigned short*)&o;
        #pragma unroll
        for (int u = 0; u < 4; ++u) {
            float2x b01 = bf2up(bwv[u * 2]);
            float2x b23 = bf2up(bwv[u * 2 + 1]);
            float2x d01 = bf2up(dwv[u * 2]);
            float2x d23 = bf2up(dwv[u * 2 + 1]);
            float2x t01 = max2(cA01 * b01, cC01 * d01);
            float2x t23 = max2(cA23 * b23, cC23 * d23);
            float p = (t01[0] + t01[1]) + (t23[0] + t23[1]);
            op[u] = f2bf((av[t][u] > 0.1f) ? p : 0.f);
        }
        *(ushort4*)&orow[jv * 4] = o;
    }
}

// ============================================================
// K3: partials[s] = attn[:, ks] @ h[ks, :]  (bf16 MFMA, reg prefetch)
// ============================================================
__global__ __launch_bounds__(256) void k_out_gemm(const unsigned short* __restrict__ attn,
                                                  const unsigned short* __restrict__ hT,
                                                  float* __restrict__ partials) {
    __shared__ __align__(16) unsigned short lds_a[64 * 40];
    __shared__ __align__(16) unsigned short lds_h[256 * 40];
    const int tid  = threadIdx.x;
    const int w    = tid >> 6;
    const int lane = tid & 63;
    const int lidx = lane & 15;
    const int quad = lane >> 4;
    const int i0    = blockIdx.x * 64;
    const int kbase = blockIdx.y * (NN / KSPLIT);
    const int srow = tid >> 3;      // 0..31
    const int skq  = tid & 7;

    float4x acc[4][4];
    #pragma unroll
    for (int p = 0; p < 4; ++p)
        #pragma unroll
        for (int q = 0; q < 4; ++q)
            acc[p][q] = (float4x){0.f, 0.f, 0.f, 0.f};

    ushort4 pa[2], ph[8];
    #pragma unroll
    for (int it = 0; it < 2; ++it)
        pa[it] = *(const ushort4*)&attn[(size_t)(i0 + it * 32 + srow) * NN + kbase + skq * 4];
    #pragma unroll
    for (int it = 0; it < 8; ++it)
        ph[it] = *(const ushort4*)&hT[(size_t)(it * 32 + srow) * NN + kbase + skq * 4];

    const int KSTEPS = (NN / KSPLIT) / 32;   // 16
    for (int ks = 0; ks < KSTEPS; ++ks) {
        __syncthreads();
        #pragma unroll
        for (int it = 0; it < 2; ++it)
            *(ushort4*)&lds_a[(it * 32 + srow) * 40 + skq * 4] = pa[it];
        #pragma unroll
        for (int it = 0; it < 8; ++it)
            *(ushort4*)&lds_h[(it * 32 + srow) * 40 + skq * 4] = ph[it];
        __syncthreads();
        if (ks < KSTEPS - 1) {
            const int ktn = kbase + (ks + 1) * 32;
            #pragma unroll
            for (int it = 0; it < 2; ++it)
                pa[it] = *(const ushort4*)&attn[(size_t)(i0 + it * 32 + srow) * NN + ktn + skq * 4];
            #pragma unroll
            for (int it = 0; it < 8; ++it)
                ph[it] = *(const ushort4*)&hT[(size_t)(it * 32 + srow) * NN + ktn + skq * 4];
        }
        short8x af[4], bfr[4];
        #pragma unroll
        for (int t = 0; t < 4; ++t) {
            af[t]  = *(const short8x*)&lds_a[(t * 16 + lidx) * 40 + quad * 8];
            bfr[t] = *(const short8x*)&lds_h[(w * 64 + t * 16 + lidx) * 40 + quad * 8];
        }
        #pragma unroll
        for (int it = 0; it < 4; ++it)
            #pragma unroll
            for (int nt = 0; nt < 4; ++nt)
                acc[it][nt] = __builtin_amdgcn_mfma_f32_16x16x32_bf16(
                    af[it], bfr[nt], acc[it][nt], 0, 0, 0);
    }
    float* pbase = partials + (size_t)blockIdx.y * NN * OUTF;
    #pragma unroll
    for (int it = 0; it < 4; ++it)
        #pragma unroll
        for (int nt = 0; nt < 4; ++nt)
            #pragma unroll
            for (int rr = 0; rr < 4; ++rr) {
                int row = i0 + it * 16 + quad * 4 + rr;
                int col = w * 64 + nt * 16 + lidx;
                pbase[(size_t)row * OUTF + col] = acc[it][nt][rr];
            }
}

// ============================================================
// K4: out = sum_s partials[s] + bias
// ============================================================
__global__ __launch_bounds__(256) void k_reduce_out(const float* __restrict__ partials,
                                                    const float* __restrict__ bias,
                                                    float* __restrict__ out) {
    const int i = blockIdx.x;
    const int n = threadIdx.x;
    float acc = bias[n];
    #pragma unroll
    for (int s = 0; s < KSPLIT; ++s)
        acc += partials[((size_t)s * NN + i) * OUTF + n];
    out[(size_t)i * OUTF + n] = acc;
}

// ============================================================
extern "C" void kernel_launch(void* const* d_in, const int* in_sizes, int n_in,
                              void* d_out, int out_size, void* d_ws, size_t ws_size,
                              hipStream_t stream) {
    const float* feat = (const float*)d_in[0];   // [4096,512]
    const float* adj  = (const float*)d_in[1];   // [4096,4096]
    const float* W    = (const float*)d_in[2];   // [256,512]
    const float* a    = (const float*)d_in[3];   // [4,128]
    const float* bias = (const float*)d_in[4];   // [256]
    float* out = (float*)d_out;                  // [4096,256] fp32

    char* ws = (char*)d_ws;
    float*          es    = (float*)(ws + 0);                        // 64 KiB
    unsigned short* Btb   = (unsigned short*)(ws + (64u << 10));     // 32 KiB
    unsigned short* Dtb   = (unsigned short*)(ws + (96u << 10));     // 32 KiB
    unsigned short* hT    = (unsigned short*)(ws + (256u << 10));    // 2 MiB
    unsigned short* attn  = (unsigned short*)(ws + (2560u << 10));   // 32 MiB
    unsigned short* featb = (unsigned short*)(ws + (2560u << 10));   // 4 MiB (dead before attn written)
    unsigned short* Wb    = (unsigned short*)(ws + (6656u << 10));   // 256 KiB (dead before attn)
    float*          partials = (float*)(ws + (35328u << 10));        // 32 MiB

    k_cast      <<<2176,             256, 0, stream>>>(feat, W, featb, Wb);
    k_hedge     <<<64,               256, 0, stream>>>(featb, Wb, a, hT, es, Btb, Dtb);
    k_attn      <<<NN,               256, 0, stream>>>(adj, es, Btb, Dtb, attn);
    k_out_gemm  <<<dim3(64, KSPLIT), 256, 0, stream>>>(attn, hT, partials);
    k_reduce_out<<<NN,               256, 0, stream>>>(partials, bias, out);
}

// Round 2
// 177.918 us; speedup vs baseline: 1.0488x; 1.0488x over previous
//
#include <hip/hip_runtime.h>
#include <math.h>

// ---- problem constants ----
#define NN      4096   // nodes
#define INF_    512    // in features
#define OUTF    256    // out features
#define NHEAD   4
#define HDIM    64
#define KSPLIT  8

typedef __attribute__((ext_vector_type(8))) short  short8x;
typedef __attribute__((ext_vector_type(4))) float  float4x;
typedef __attribute__((ext_vector_type(2))) float  float2x;

__device__ __forceinline__ unsigned short f2bf(float x) {
    union { float f; unsigned int u; } c; c.f = x;
    unsigned int r = (c.u + 0x7FFFu + ((c.u >> 16) & 1u)) >> 16;
    return (unsigned short)r;
}
// unpack a bf16 pair (one dword) into float2 {lo, hi}
__device__ __forceinline__ float2x bf2up(unsigned int u) {
    union { unsigned int x; float f; } lo, hi;
    lo.x = u << 16; hi.x = u & 0xFFFF0000u;
    float2x r; r[0] = lo.f; r[1] = hi.f; return r;
}
__device__ __forceinline__ float2x max2(float2x a, float2x b) {
    float2x r; r[0] = fmaxf(a[0], b[0]); r[1] = fmaxf(a[1], b[1]); return r;
}

// ============================================================
// K0: cast feat and W to bf16
// ============================================================
__global__ __launch_bounds__(256) void k_cast(const float* __restrict__ feat,
                                              const float* __restrict__ W,
                                              unsigned short* __restrict__ featb,
                                              unsigned short* __restrict__ Wb) {
    const int b = blockIdx.x;
    const float* src;
    unsigned short* dst;
    int idx;
    if (b < 2048) { src = feat; dst = featb; idx = b * 1024 + threadIdx.x * 4; }
    else          { src = W;    dst = Wb;    idx = (b - 2048) * 1024 + threadIdx.x * 4; }
    float4x v = *(const float4x*)(src + idx);
    ushort4 u;
    u.x = f2bf(v[0]); u.y = f2bf(v[1]); u.z = f2bf(v[2]); u.w = f2bf(v[3]);
    *(ushort4*)(dst + idx) = u;
}

// ============================================================
// K1: h = feat @ W^T (bf16 MFMA, 64 blocks, full OUTF per block)
// epilogue: hT bf16 write + es/ed per-head dots from registers
// -> es + exp tables Bt=exp(ed), Dt=exp(0.2 ed)
// ============================================================
__global__ __launch_bounds__(256) void k_hedge(const unsigned short* __restrict__ featb,
                                               const unsigned short* __restrict__ Wb,
                                               const float* __restrict__ a,
                                               unsigned short* __restrict__ hT,
                                               float* __restrict__ es,
                                               unsigned short* __restrict__ Bt,
                                               unsigned short* __restrict__ Dt) {
    __shared__ __align__(16) unsigned short lds_f[64 * 40];
    __shared__ __align__(16) unsigned short lds_w[256 * 40];
    const int tid  = threadIdx.x;
    const int w    = tid >> 6;
    const int lane = tid & 63;
    const int lidx = lane & 15;
    const int quad = lane >> 4;
    const int i0   = blockIdx.x * 64;
    const int sr = tid >> 2;
    const int skq = (tid & 3) * 8;

    float4x acc[4][4];
    #pragma unroll
    for (int p = 0; p < 4; ++p)
        #pragma unroll
        for (int q = 0; q < 4; ++q)
            acc[p][q] = (float4x){0.f, 0.f, 0.f, 0.f};

    for (int kt = 0; kt < INF_; kt += 32) {
        __syncthreads();
        *(ushort4*)&lds_f[sr * 40 + skq]     = *(const ushort4*)&featb[(size_t)(i0 + sr) * INF_ + kt + skq];
        *(ushort4*)&lds_f[sr * 40 + skq + 4] = *(const ushort4*)&featb[(size_t)(i0 + sr) * INF_ + kt + skq + 4];
        #pragma unroll
        for (int itr = 0; itr < 4; ++itr) {
            int n = itr * 64 + sr;
            *(ushort4*)&lds_w[n * 40 + skq]     = *(const ushort4*)&Wb[(size_t)n * INF_ + kt + skq];
            *(ushort4*)&lds_w[n * 40 + skq + 4] = *(const ushort4*)&Wb[(size_t)n * INF_ + kt + skq + 4];
        }
        __syncthreads();
        short8x af[4], bw[4];
        #pragma unroll
        for (int t = 0; t < 4; ++t) {
            af[t] = *(const short8x*)&lds_f[(t * 16 + lidx) * 40 + quad * 8];
            bw[t] = *(const short8x*)&lds_w[(w * 64 + t * 16 + lidx) * 40 + quad * 8];
        }
        #pragma unroll
        for (int it = 0; it < 4; ++it)
            #pragma unroll
            for (int nt = 0; nt < 4; ++nt)
                acc[it][nt] = __builtin_amdgcn_mfma_f32_16x16x32_bf16(
                    af[it], bw[nt], acc[it][nt], 0, 0, 0);
    }
    // ---- hT write (D layout: col=lane&15 block w*64+nt*16, row=quad*4+r) ----
    #pragma unroll
    for (int it = 0; it < 4; ++it)
        #pragma unroll
        for (int nt = 0; nt < 4; ++nt) {
            int col = w * 64 + nt * 16 + lidx;
            int m0r = i0 + it * 16 + quad * 4;
            ushort4 u;
            u.x = f2bf(acc[it][nt][0]); u.y = f2bf(acc[it][nt][1]);
            u.z = f2bf(acc[it][nt][2]); u.w = f2bf(acc[it][nt][3]);
            *(ushort4*)&hT[(size_t)col * NN + m0r] = u;
        }
    // ---- es/ed epilogue: head = w; col_d = nt*16 + lidx ----
    float asrc[4], adst[4];
    #pragma unroll
    for (int nt = 0; nt < 4; ++nt) {
        asrc[nt] = a[w * 2 * HDIM + nt * 16 + lidx];
        adst[nt] = a[w * 2 * HDIM + HDIM + nt * 16 + lidx];
    }
    #pragma unroll
    for (int it = 0; it < 4; ++it)
        #pragma unroll
        for (int r = 0; r < 4; ++r) {
            float s = 0.f, d = 0.f;
            #pragma unroll
            for (int nt = 0; nt < 4; ++nt) {
                s += acc[it][nt][r] * asrc[nt];
                d += acc[it][nt][r] * adst[nt];
            }
            #pragma unroll
            for (int off = 1; off < 16; off <<= 1) {
                s += __shfl_xor(s, off);
                d += __shfl_xor(d, off);
            }
            if (lidx == 0) {
                int row = i0 + it * 16 + quad * 4 + r;
                es[row * NHEAD + w] = s;
                Bt[row * NHEAD + w] = f2bf(__expf(d));
                Dt[row * NHEAD + w] = f2bf(__expf(0.2f * d));
            }
        }
}

// ============================================================
// K2: fused den + attn-row write. 1 row/block, 4096 blocks.
// Max-trick: exp(leaky(es+ed)) = max(A*b, C*d). Pass 1 computes
// masked per-head terms m_h = mask*max(A*b, C*d) and KEEPS THEM
// IN REGISTERS (64 VGPR). Pass 2 is a pure register dot with
// sc[h] = 0.25/den[h] -- zero table re-reads, zero unpack.
// ============================================================
__global__ __launch_bounds__(256) void k_attn(const float* __restrict__ adj,
                                              const float* __restrict__ es,
                                              const unsigned short* __restrict__ Bt,
                                              const unsigned short* __restrict__ Dt,
                                              unsigned short* __restrict__ attn) {
    __shared__ float red[4][4];
    __shared__ float cfs[4];
    const int tid = threadIdx.x;
    const int wv  = tid >> 6;
    const int lane = tid & 63;
    const int i = blockIdx.x;

    const float4x esv = ((const float4x*)es)[i];
    float2x A01, A23, C01, C23;
    A01[0] = __expf(esv[0]); A01[1] = __expf(esv[1]);
    A23[0] = __expf(esv[2]); A23[1] = __expf(esv[3]);
    C01[0] = __expf(0.2f * esv[0]); C01[1] = __expf(0.2f * esv[1]);
    C23[0] = __expf(0.2f * esv[2]); C23[1] = __expf(0.2f * esv[3]);

    const float4x* arow4 = (const float4x*)(adj + (size_t)i * NN);
    const uint4* B4 = (const uint4*)Bt;
    const uint4* D4 = (const uint4*)Dt;

    // ---- pass 1: masked per-head terms -> registers; accumulate den ----
    float2x m01[4][4], m23[4][4];
    float2x den01 = (float2x){0.f, 0.f};
    float2x den23 = (float2x){0.f, 0.f};
    #pragma unroll
    for (int t = 0; t < 4; ++t) {
        int jv = t * 256 + tid;
        float4x av = arow4[jv];
        uint4 bu0 = B4[jv * 2], bu1 = B4[jv * 2 + 1];
        uint4 du0 = D4[jv * 2], du1 = D4[jv * 2 + 1];
        unsigned int bwv[8] = {bu0.x, bu0.y, bu0.z, bu0.w, bu1.x, bu1.y, bu1.z, bu1.w};
        unsigned int dwv[8] = {du0.x, du0.y, du0.z, du0.w, du1.x, du1.y, du1.z, du1.w};
        #pragma unroll
        for (int u = 0; u < 4; ++u) {
            float2x b01 = bf2up(bwv[u * 2]);
            float2x b23 = bf2up(bwv[u * 2 + 1]);
            float2x d01 = bf2up(dwv[u * 2]);
            float2x d23 = bf2up(dwv[u * 2 + 1]);
            float mf = (av[u] > 0.1f) ? 1.f : 0.f;
            float2x mf2; mf2[0] = mf; mf2[1] = mf;
            m01[t][u] = mf2 * max2(A01 * b01, C01 * d01);
            m23[t][u] = mf2 * max2(A23 * b23, C23 * d23);
            den01 += m01[t][u];
            den23 += m23[t][u];
        }
    }
    float dh[4] = {den01[0], den01[1], den23[0], den23[1]};
    #pragma unroll
    for (int off = 1; off < 64; off <<= 1) {
        #pragma unroll
        for (int h = 0; h < 4; ++h)
            dh[h] += __shfl_xor(dh[h], off);
    }
    if (lane == 0) {
        #pragma unroll
        for (int h = 0; h < 4; ++h) red[wv][h] = dh[h];
    }
    __syncthreads();
    if (tid < 4)
        cfs[tid] = red[0][tid] + red[1][tid] + red[2][tid] + red[3][tid];
    __syncthreads();
    float sc[4];
    #pragma unroll
    for (int h = 0; h < 4; ++h) {
        float den = cfs[h];
        sc[h] = den > 0.f ? 0.25f / den : 0.f;
    }

    // ---- pass 2: pure register dot, store ----
    unsigned short* orow = attn + (size_t)i * NN;
    #pragma unroll
    for (int t = 0; t < 4; ++t) {
        int jv = t * 256 + tid;
        ushort4 o;
        unsigned short* op = (unsigned short*)&o;
        #pragma unroll
        for (int u = 0; u < 4; ++u) {
            float p = sc[0] * m01[t][u][0] + sc[1] * m01[t][u][1]
                    + sc[2] * m23[t][u][0] + sc[3] * m23[t][u][1];
            op[u] = f2bf(p);
        }
        *(ushort4*)&orow[jv * 4] = o;
    }
}

// ============================================================
// K3: partials[s] = attn[:, ks] @ h[ks, :]  (bf16 MFMA, reg prefetch)
// 32-row blocks, grid (128, KSPLIT) = 1024 blocks -> 4 blocks/CU
// ============================================================
__global__ __launch_bounds__(256) void k_out_gemm(const unsigned short* __restrict__ attn,
                                                  const unsigned short* __restrict__ hT,
                                                  float* __restrict__ partials) {
    __shared__ __align__(16) unsigned short lds_a[32 * 40];
    __shared__ __align__(16) unsigned short lds_h[256 * 40];
    const int tid  = threadIdx.x;
    const int w    = tid >> 6;
    const int lane = tid & 63;
    const int lidx = lane & 15;
    const int quad = lane >> 4;
    const int i0    = blockIdx.x * 32;
    const int kbase = blockIdx.y * (NN / KSPLIT);
    const int srow = tid >> 3;      // 0..31
    const int skq  = tid & 7;

    float4x acc[2][4];
    #pragma unroll
    for (int p = 0; p < 2; ++p)
        #pragma unroll
        for (int q = 0; q < 4; ++q)
            acc[p][q] = (float4x){0.f, 0.f, 0.f, 0.f};

    ushort4 pa, ph[8];
    pa = *(const ushort4*)&attn[(size_t)(i0 + srow) * NN + kbase + skq * 4];
    #pragma unroll
    for (int it = 0; it < 8; ++it)
        ph[it] = *(const ushort4*)&hT[(size_t)(it * 32 + srow) * NN + kbase + skq * 4];

    const int KSTEPS = (NN / KSPLIT) / 32;   // 16
    for (int ks = 0; ks < KSTEPS; ++ks) {
        __syncthreads();
        *(ushort4*)&lds_a[srow * 40 + skq * 4] = pa;
        #pragma unroll
        for (int it = 0; it < 8; ++it)
            *(ushort4*)&lds_h[(it * 32 + srow) * 40 + skq * 4] = ph[it];
        __syncthreads();
        if (ks < KSTEPS - 1) {
            const int ktn = kbase + (ks + 1) * 32;
            pa = *(const ushort4*)&attn[(size_t)(i0 + srow) * NN + ktn + skq * 4];
            #pragma unroll
            for (int it = 0; it < 8; ++it)
                ph[it] = *(const ushort4*)&hT[(size_t)(it * 32 + srow) * NN + ktn + skq * 4];
        }
        short8x af[2], bfr[4];
        #pragma unroll
        for (int t = 0; t < 2; ++t)
            af[t]  = *(const short8x*)&lds_a[(t * 16 + lidx) * 40 + quad * 8];
        #pragma unroll
        for (int t = 0; t < 4; ++t)
            bfr[t] = *(const short8x*)&lds_h[(w * 64 + t * 16 + lidx) * 40 + quad * 8];
        #pragma unroll
        for (int it = 0; it < 2; ++it)
            #pragma unroll
            for (int nt = 0; nt < 4; ++nt)
                acc[it][nt] = __builtin_amdgcn_mfma_f32_16x16x32_bf16(
                    af[it], bfr[nt], acc[it][nt], 0, 0, 0);
    }
    float* pbase = partials + (size_t)blockIdx.y * NN * OUTF;
    #pragma unroll
    for (int it = 0; it < 2; ++it)
        #pragma unroll
        for (int nt = 0; nt < 4; ++nt)
            #pragma unroll
            for (int rr = 0; rr < 4; ++rr) {
                int row = i0 + it * 16 + quad * 4 + rr;
                int col = w * 64 + nt * 16 + lidx;
                pbase[(size_t)row * OUTF + col] = acc[it][nt][rr];
            }
}

// ============================================================
// K4: out = sum_s partials[s] + bias
// ============================================================
__global__ __launch_bounds__(256) void k_reduce_out(const float* __restrict__ partials,
                                                    const float* __restrict__ bias,
                                                    float* __restrict__ out) {
    const int i = blockIdx.x;
    const int n = threadIdx.x;
    float acc = bias[n];
    #pragma unroll
    for (int s = 0; s < KSPLIT; ++s)
        acc += partials[((size_t)s * NN + i) * OUTF + n];
    out[(size_t)i * OUTF + n] = acc;
}

// ============================================================
extern "C" void kernel_launch(void* const* d_in, const int* in_sizes, int n_in,
                              void* d_out, int out_size, void* d_ws, size_t ws_size,
                              hipStream_t stream) {
    const float* feat = (const float*)d_in[0];   // [4096,512]
    const float* adj  = (const float*)d_in[1];   // [4096,4096]
    const float* W    = (const float*)d_in[2];   // [256,512]
    const float* a    = (const float*)d_in[3];   // [4,128]
    const float* bias = (const float*)d_in[4];   // [256]
    float* out = (float*)d_out;                  // [4096,256] fp32

    char* ws = (char*)d_ws;
    float*          es    = (float*)(ws + 0);                        // 64 KiB
    unsigned short* Btb   = (unsigned short*)(ws + (64u << 10));     // 32 KiB
    unsigned short* Dtb   = (unsigned short*)(ws + (96u << 10));     // 32 KiB
    unsigned short* hT    = (unsigned short*)(ws + (256u << 10));    // 2 MiB
    unsigned short* attn  = (unsigned short*)(ws + (2560u << 10));   // 32 MiB
    unsigned short* featb = (unsigned short*)(ws + (2560u << 10));   // 4 MiB (dead before attn written)
    unsigned short* Wb    = (unsigned short*)(ws + (6656u << 10));   // 256 KiB (dead before attn)
    float*          partials = (float*)(ws + (35328u << 10));        // 32 MiB

    k_cast      <<<2176,              256, 0, stream>>>(feat, W, featb, Wb);
    k_hedge     <<<64,                256, 0, stream>>>(featb, Wb, a, hT, es, Btb, Dtb);
    k_attn      <<<NN,                256, 0, stream>>>(adj, es, Btb, Dtb, attn);
    k_out_gemm  <<<dim3(128, KSPLIT), 256, 0, stream>>>(attn, hT, partials);
    k_reduce_out<<<NN,                256, 0, stream>>>(partials, bias, out);
}